// Round 8
// baseline (613.653 us; speedup 1.0000x reference)
//
#include <hip/hip_runtime.h>

#define IN_DIM 256
#define HID 256
#define SCAN_CHUNK 512

typedef unsigned short ushort_t;
typedef __attribute__((ext_vector_type(8))) short short8;
typedef __attribute__((ext_vector_type(4))) float floatx4;

__device__ __forceinline__ float b2f(ushort_t h) {
    union { unsigned int u; float f; } c; c.u = ((unsigned int)h) << 16; return c.f;
}
__device__ __forceinline__ ushort_t f2b(float f) {  // round-to-nearest-even
    union { float f; unsigned int u; } c; c.f = f;
    unsigned int u = c.u;
    unsigned int r = (u + 0x7fffu + ((u >> 16) & 1u)) >> 16;
    return (ushort_t)r;
}

// ---------------- degree ----------------
__global__ void k_count_deg(const int* __restrict__ dst, int* __restrict__ deg, int E) {
    int e = blockIdx.x * blockDim.x + threadIdx.x;
    if (e < E) atomicAdd(&deg[dst[e]], 1);
}

// ---------------- scan ----------------
__global__ __launch_bounds__(64) void k_chunk_sum(const int* __restrict__ deg,
                                                  int* __restrict__ partials, int N) {
    int lane = threadIdx.x;
    int base = blockIdx.x * SCAN_CHUNK + lane * 8;
    int s = 0;
#pragma unroll
    for (int i = 0; i < 8; ++i) s += (base + i < N) ? deg[base + i] : 0;
#pragma unroll
    for (int off = 32; off > 0; off >>= 1) s += __shfl_down(s, off, 64);
    if (lane == 0) partials[blockIdx.x] = s;
}

__global__ void k_scan_partials(int* __restrict__ partials, int nb) {
    if (threadIdx.x == 0 && blockIdx.x == 0) {
        int run = 0;
        for (int i = 0; i < nb; ++i) { int v = partials[i]; partials[i] = run; run += v; }
    }
}

__global__ __launch_bounds__(64) void k_scan_chunks(const int* __restrict__ deg,
                                                    const int* __restrict__ partials,
                                                    int* __restrict__ row_start,
                                                    int* __restrict__ cursor, int N) {
    int lane = threadIdx.x;
    int base = blockIdx.x * SCAN_CHUNK + lane * 8;
    int v[8]; int lsum = 0;
#pragma unroll
    for (int i = 0; i < 8; ++i) { v[i] = (base + i < N) ? deg[base + i] : 0; lsum += v[i]; }
    int pre = lsum;
#pragma unroll
    for (int off = 1; off < 64; off <<= 1) {
        int t = __shfl_up(pre, off, 64);
        if (lane >= off) pre += t;
    }
    pre -= lsum;
    int run = partials[blockIdx.x] + pre;
#pragma unroll
    for (int i = 0; i < 8; ++i) {
        if (base + i < N) { row_start[base + i] = run; cursor[base + i] = run; }
        run += v[i];
    }
}

// csr[pos] = {src, eid} packed
__global__ void k_bucket(const int* __restrict__ src, const int* __restrict__ dst,
                         int* __restrict__ cursor, int2* __restrict__ csr, int E) {
    int e = blockIdx.x * blockDim.x + threadIdx.x;
    if (e < E) {
        int pos = atomicAdd(&cursor[dst[e]], 1);
        csr[pos] = make_int2(src[e], e);
    }
}

// ---------------- cast x -> bf16 ----------------
__global__ __launch_bounds__(256) void k_cast(const float* __restrict__ x,
                                              ushort_t* __restrict__ xb, int n4) {
    int i = blockIdx.x * blockDim.x + threadIdx.x;
    if (i >= n4) return;
    float4 v = ((const float4*)x)[i];
    ushort4 o;
    o.x = f2b(v.x); o.y = f2b(v.y); o.z = f2b(v.z); o.w = f2b(v.w);
    ((ushort4*)xb)[i] = o;
}

// ---------------- weight prep: fp32 [256][256] -> MFMA B-frag order, single bf16 plane ------
// WF layout: [(kb*nbTot + nb)][512] ushorts; within: lane*8 + j
// element: k = kb*32 + (lane>>4)*8 + j ; n_local = nbL*16 + (lane&15)
__global__ __launch_bounds__(64) void k_wprep(const float* __restrict__ Wsrc,
                                              ushort_t* __restrict__ WF,
                                              int nbTot, int nb0) {
    int lane = threadIdx.x;
    int kb = blockIdx.x >> 4, nbL = blockIdx.x & 15;
    int k = kb * 32 + (lane >> 4) * 8;
    int n = nbL * 16 + (lane & 15);
    size_t dstb = (size_t)(kb * nbTot + nb0 + nbL) * 512 + lane * 8;
#pragma unroll
    for (int j = 0; j < 8; ++j) {
        WF[dstb + j] = f2b(Wsrc[(size_t)(k + j) * 256 + n]);
    }
}

// ---------------- gather-aggregate: one wave/node, 8 rows in flight, batched indices --------
// Wave-uniform inner loop; shfl under full exec; loads unconditional (clamped idx), adds predicated.
__global__ __launch_bounds__(256) void k_gather(const ushort_t* __restrict__ X,
                                                const int2* __restrict__ csr,
                                                const int* __restrict__ row_start,
                                                const int* __restrict__ deg,
                                                ushort_t* __restrict__ agg, int N) {
    int lane = threadIdx.x & 63;
    int node = blockIdx.x * 4 + (threadIdx.x >> 6);
    if (node >= N) return;
    int quad = lane >> 4, l16 = lane & 15;
    int start = row_start[node];
    int cnt = deg[node];
    const int2* sp = csr + start;
    float acc[16] = {};
    for (int b = 0; b < cnt; b += 64) {
        int nb = min(64, cnt - b);
        int sidx = (lane < nb) ? sp[b + lane].x : 0;   // one coalesced batch load
        for (int j8 = 0; j8 < nb; j8 += 8) {           // uniform across the wave
            int jA = j8 + quad, jB = j8 + 4 + quad;
            bool vA = jA < nb, vB = jB < nb;
            int sA = __shfl(sidx, vA ? jA : 0, 64);
            int sB = __shfl(sidx, vB ? jB : 0, 64);
            const ushort_t* rowA = X + (size_t)sA * HID + l16 * 16;
            const ushort_t* rowB = X + (size_t)sB * HID + l16 * 16;
            short8 a0 = *(const short8*)(rowA);
            short8 a1 = *(const short8*)(rowA + 8);
            short8 b0 = *(const short8*)(rowB);
            short8 b1 = *(const short8*)(rowB + 8);
            if (vA) {
#pragma unroll
                for (int i = 0; i < 8; ++i) {
                    acc[i]     += b2f((ushort_t)a0[i]);
                    acc[8 + i] += b2f((ushort_t)a1[i]);
                }
            }
            if (vB) {
#pragma unroll
                for (int i = 0; i < 8; ++i) {
                    acc[i]     += b2f((ushort_t)b0[i]);
                    acc[8 + i] += b2f((ushort_t)b1[i]);
                }
            }
        }
    }
#pragma unroll
    for (int i = 0; i < 16; ++i) {
        acc[i] += __shfl_down(acc[i], 32, 64);
        acc[i] += __shfl_down(acc[i], 16, 64);
    }
    if (quad == 0) {
        float sc = 1.0f / (float)max(cnt, 1);
        short8 o0, o1;
#pragma unroll
        for (int i = 0; i < 8; ++i) {
            o0[i] = (short)f2b(acc[i] * sc);
            o1[i] = (short)f2b(acc[8 + i] * sc);
        }
        ushort_t* op = agg + (size_t)node * HID + l16 * 16;
        *(short8*)(op) = o0;
        *(short8*)(op + 8) = o1;
    }
}

// ---------------- MFMA GEMM, barrier-free: C = act( A1@W1 + A2@W2 + bias ) ------------------
// No LDS: A-fragments loaded directly from global (row-major, 16B/lane, quad-contiguous 64B
// per row — L1/L2 served, reused across waves/blocks). B in frag order. No __syncthreads at all.
__global__ __launch_bounds__(256) void k_mfma(const ushort_t* __restrict__ A1,
                                              const ushort_t* __restrict__ WF1,
                                              const ushort_t* __restrict__ A2,
                                              const ushort_t* __restrict__ WF2,
                                              const float* __restrict__ bias, int relu,
                                              int M, int nbTot,
                                              ushort_t* __restrict__ C,
                                              ushort_t* __restrict__ C2) {
    const int tid = threadIdx.x;
    const int lane = tid & 63;
    const int w = tid >> 6;
    const int wm = w >> 1, wn = w & 1;
    const int quad = lane >> 4, l16 = lane & 15;
    const int m0 = blockIdx.y * 64;
    const int n0 = blockIdx.x * 64;

    int r0 = m0 + wm * 32 + l16;      if (r0 >= M) r0 = M - 1;
    int r1 = m0 + wm * 32 + 16 + l16; if (r1 >= M) r1 = M - 1;
    const int nbBase = (n0 >> 4) + wn * 2;

    floatx4 acc[2][2] = {};

    for (int op = 0; op < 2; ++op) {
        const ushort_t* A = op ? A2 : A1;
        const ushort_t* WF = op ? WF2 : WF1;
        if (A == nullptr) continue;
        const ushort_t* ap0 = A + (size_t)r0 * 256 + quad * 8;
        const ushort_t* ap1 = A + (size_t)r1 * 256 + quad * 8;
        const ushort_t* wp = WF + (size_t)nbBase * 512 + lane * 8;
#pragma unroll
        for (int kb = 0; kb < 8; ++kb) {
            short8 a0 = *(const short8*)(ap0 + kb * 32);
            short8 a1 = *(const short8*)(ap1 + kb * 32);
            const ushort_t* wkb = wp + (size_t)kb * nbTot * 512;
            short8 bh0 = *(const short8*)(wkb);
            short8 bh1 = *(const short8*)(wkb + 512);
            acc[0][0] = __builtin_amdgcn_mfma_f32_16x16x32_bf16(a0, bh0, acc[0][0], 0, 0, 0);
            acc[0][1] = __builtin_amdgcn_mfma_f32_16x16x32_bf16(a0, bh1, acc[0][1], 0, 0, 0);
            acc[1][0] = __builtin_amdgcn_mfma_f32_16x16x32_bf16(a1, bh0, acc[1][0], 0, 0, 0);
            acc[1][1] = __builtin_amdgcn_mfma_f32_16x16x32_bf16(a1, bh1, acc[1][1], 0, 0, 0);
        }
    }

    // epilogue: C/D layout col=lane&15, row=(lane>>4)*4+reg
#pragma unroll
    for (int mi = 0; mi < 2; ++mi) {
#pragma unroll
        for (int nj = 0; nj < 2; ++nj) {
            int col = n0 + wn * 32 + nj * 16 + l16;
            float b = bias ? bias[col] : 0.f;
            int rbase = m0 + wm * 32 + mi * 16 + quad * 4;
            ushort_t* dstp = C;
            int c = col;
            if (C2 && col >= 256) { dstp = C2; c = col - 256; }
#pragma unroll
            for (int reg = 0; reg < 4; ++reg) {
                int r = rbase + reg;
                if (r >= M) continue;
                float v = acc[mi][nj][reg] + b;
                if (relu) v = fmaxf(v, 0.f);
                dstp[(size_t)r * 256 + c] = f2b(v);
            }
        }
    }
}

// ---------------- edge MLP: persistent waves, half-wave per edge, unroll 2, batched idx ------
// All __shfl execute under full exec: j0 loop is wave-uniform, validity via ternaries.
__global__ __launch_bounds__(256) void k_edge(const ushort_t* __restrict__ P,
                                              const ushort_t* __restrict__ Q,
                                              const int2* __restrict__ csr,
                                              const int* __restrict__ row_start,
                                              const int* __restrict__ deg,
                                              const float* __restrict__ bm1,
                                              const float* __restrict__ Wm2,
                                              const float* __restrict__ bm2,
                                              float* __restrict__ out, int N, int stride) {
    int lane = threadIdx.x & 63;
    int wid = blockIdx.x * 4 + (threadIdx.x >> 6);
    int half = lane >> 5, l32 = lane & 31;

    // wave-lifetime constants: channels l32*8 .. +7
    float w0[8], w1[8], bb[8];
    const float* bp = bm1 + l32 * 8;
    const float2* wp = (const float2*)Wm2 + l32 * 8;
#pragma unroll
    for (int i = 0; i < 8; ++i) {
        float2 wv = wp[i];
        w0[i] = wv.x; w1[i] = wv.y;
        bb[i] = bp[i];
    }
    float bo0 = bm2[0], bo1 = bm2[1];

    for (int node = wid; node < N; node += stride) {
        int start = row_start[node];
        int cnt = deg[node];
        if (cnt == 0) continue;

        short8 qv = *(const short8*)(Q + (size_t)node * HID + l32 * 8);
        float qb[8];
#pragma unroll
        for (int i = 0; i < 8; ++i) qb[i] = b2f((ushort_t)qv[i]) + bb[i];

        const int2* sp = csr + start;
        for (int b = 0; b < cnt; b += 64) {
            int nb = min(64, cnt - b);
            int2 se = (lane < nb) ? sp[b + lane] : make_int2(0, 0);
            for (int j0 = 0; j0 < nb; j0 += 4) {
                int jA = j0 + half;
                int jB = j0 + 2 + half;
                bool vA = jA < nb, vB = jB < nb;
                int iA = vA ? jA : 0, iB = vB ? jB : 0;
                int sA = __shfl(se.x, iA, 64);
                int sB = __shfl(se.x, iB, 64);
                short8 pA = *(const short8*)(P + (size_t)sA * HID + l32 * 8);
                short8 pB = *(const short8*)(P + (size_t)sB * HID + l32 * 8);
                float aA0 = 0.f, aA1 = 0.f, aB0 = 0.f, aB1 = 0.f;
#pragma unroll
                for (int i = 0; i < 8; ++i) {
                    float hA = fmaxf(b2f((ushort_t)pA[i]) + qb[i], 0.f);
                    float hB = fmaxf(b2f((ushort_t)pB[i]) + qb[i], 0.f);
                    aA0 += hA * w0[i]; aA1 += hA * w1[i];
                    aB0 += hB * w0[i]; aB1 += hB * w1[i];
                }
#pragma unroll
                for (int off = 16; off > 0; off >>= 1) {
                    aA0 += __shfl_down(aA0, off, 32);
                    aA1 += __shfl_down(aA1, off, 32);
                    aB0 += __shfl_down(aB0, off, 32);
                    aB1 += __shfl_down(aB1, off, 32);
                }
                int eA = __shfl(se.y, iA, 64);
                int eB = __shfl(se.y, iB, 64);
                if (l32 == 0) {
                    if (vA) {
                        float2 o; o.x = aA0 + bo0; o.y = aA1 + bo1;
                        ((float2*)out)[eA] = o;
                    }
                    if (vB) {
                        float2 o; o.x = aB0 + bo0; o.y = aB1 + bo1;
                        ((float2*)out)[eB] = o;
                    }
                }
            }
        }
    }
}

extern "C" void kernel_launch(void* const* d_in, const int* in_sizes, int n_in,
                              void* d_out, int out_size, void* d_ws, size_t ws_size,
                              hipStream_t stream) {
    const float* x   = (const float*)d_in[0];
    const int*   ei  = (const int*)d_in[1];
    const float* W1l = (const float*)d_in[2];
    const float* b1l = (const float*)d_in[3];
    const float* W1r = (const float*)d_in[4];
    const float* W2l = (const float*)d_in[5];
    const float* b2l = (const float*)d_in[6];
    const float* W2r = (const float*)d_in[7];
    const float* Wm1 = (const float*)d_in[8];
    const float* bm1 = (const float*)d_in[9];
    const float* Wm2 = (const float*)d_in[10];
    const float* bm2 = (const float*)d_in[11];

    const int N = in_sizes[0] / IN_DIM;   // 50000
    const int E = in_sizes[1] / 2;        // 800000
    const int* src = ei;
    const int* dst = ei + E;
    const int NB = (N + SCAN_CHUNK - 1) / SCAN_CHUNK;

    // ---- workspace ----
    char* ws = (char*)d_ws;
    size_t off = 0;
    auto alloc = [&](size_t bytes) { void* p = ws + off; off = (off + bytes + 255) & ~(size_t)255; return p; };
    int* deg       = (int*)alloc((size_t)N * 4);
    int* row_start = (int*)alloc((size_t)N * 4);
    int* cursor    = (int*)alloc((size_t)N * 4);
    int* partials  = (int*)alloc((size_t)(NB + 1) * 4);
    int2* csr      = (int2*)alloc((size_t)E * 8);
    size_t matB = (size_t)N * HID * sizeof(ushort_t);          // 25.6 MB
    ushort_t* xb   = (ushort_t*)alloc(matB);
    ushort_t* aggB = (ushort_t*)alloc(matB);
    ushort_t* h1b  = (ushort_t*)alloc(matB);
    ushort_t* h2b  = (ushort_t*)alloc(matB);
    ushort_t* Pb   = (ushort_t*)alloc(matB);
    ushort_t* Qb   = (ushort_t*)alloc(matB);
    size_t wfB  = (size_t)8 * 16 * 512 * sizeof(ushort_t);      // 128 KB (single plane)
    ushort_t* WF1l = (ushort_t*)alloc(wfB);
    ushort_t* WF1r = (ushort_t*)alloc(wfB);
    ushort_t* WF2l = (ushort_t*)alloc(wfB);
    ushort_t* WF2r = (ushort_t*)alloc(wfB);
    ushort_t* WFm  = (ushort_t*)alloc(wfB * 2);                 // nbTot=32
    float* out = (float*)d_out;

    int nwg = (N + 3) / 4;
    int mrows = (N + 63) / 64;

    // ---- CSR build ----
    hipMemsetAsync(deg, 0, (size_t)N * 4, stream);
    k_count_deg<<<(E + 255) / 256, 256, 0, stream>>>(dst, deg, E);
    k_chunk_sum<<<NB, 64, 0, stream>>>(deg, partials, N);
    k_scan_partials<<<1, 64, 0, stream>>>(partials, NB);
    k_scan_chunks<<<NB, 64, 0, stream>>>(deg, partials, row_start, cursor, N);
    k_bucket<<<(E + 255) / 256, 256, 0, stream>>>(src, dst, cursor, csr, E);

    // ---- casts / weight prep ----
    k_cast<<<(N * HID / 4 + 255) / 256, 256, 0, stream>>>(x, xb, N * HID / 4);
    k_wprep<<<128, 64, 0, stream>>>(W1l, WF1l, 16, 0);
    k_wprep<<<128, 64, 0, stream>>>(W1r, WF1r, 16, 0);
    k_wprep<<<128, 64, 0, stream>>>(W2l, WF2l, 16, 0);
    k_wprep<<<128, 64, 0, stream>>>(W2r, WF2r, 16, 0);
    k_wprep<<<128, 64, 0, stream>>>(Wm1, WFm, 32, 0);
    k_wprep<<<128, 64, 0, stream>>>(Wm1 + (size_t)256 * 256, WFm, 32, 16);

    // ---- conv1 ----
    k_gather<<<nwg, 256, 0, stream>>>(xb, csr, row_start, deg, aggB, N);
    k_mfma<<<dim3(4, mrows), 256, 0, stream>>>(aggB, WF1l, xb, WF1r, b1l, 1, N, 16, h1b, nullptr);

    // ---- conv2 ----
    k_gather<<<nwg, 256, 0, stream>>>(h1b, csr, row_start, deg, aggB, N);
    k_mfma<<<dim3(4, mrows), 256, 0, stream>>>(aggB, WF2l, h1b, WF2r, b2l, 1, N, 16, h2b, nullptr);

    // ---- P|Q fused GEMM -> Pb, Qb ----
    k_mfma<<<dim3(8, mrows), 256, 0, stream>>>(h2b, WFm, nullptr, nullptr, nullptr, 0, N, 32, Pb, Qb);

    // ---- edge MLP (persistent waves) ----
    const int EB = 2048;                  // 8 blocks/CU
    k_edge<<<EB, 256, 0, stream>>>(Pb, Qb, csr, row_start, deg, bm1, Wm2, bm2, out, N, EB * 4);
}

// Round 9
// 572.702 us; speedup vs baseline: 1.0715x; 1.0715x over previous
//
#include <hip/hip_runtime.h>

#define IN_DIM 256
#define HID 256
#define SCAN_CHUNK 512
#define PADW 264   // 256 + 16 ushort pad: row stride = 528B = 132 dwords = 4-bank shift

typedef unsigned short ushort_t;
typedef __attribute__((ext_vector_type(8))) short short8;
typedef __attribute__((ext_vector_type(4))) float floatx4;

__device__ __forceinline__ float b2f(ushort_t h) {
    union { unsigned int u; float f; } c; c.u = ((unsigned int)h) << 16; return c.f;
}
__device__ __forceinline__ ushort_t f2b(float f) {  // round-to-nearest-even
    union { float f; unsigned int u; } c; c.f = f;
    unsigned int u = c.u;
    unsigned int r = (u + 0x7fffu + ((u >> 16) & 1u)) >> 16;
    return (ushort_t)r;
}

// ---------------- degree ----------------
__global__ void k_count_deg(const int* __restrict__ dst, int* __restrict__ deg, int E) {
    int e = blockIdx.x * blockDim.x + threadIdx.x;
    if (e < E) atomicAdd(&deg[dst[e]], 1);
}

// ---------------- scan ----------------
__global__ __launch_bounds__(64) void k_chunk_sum(const int* __restrict__ deg,
                                                  int* __restrict__ partials, int N) {
    int lane = threadIdx.x;
    int base = blockIdx.x * SCAN_CHUNK + lane * 8;
    int s = 0;
#pragma unroll
    for (int i = 0; i < 8; ++i) s += (base + i < N) ? deg[base + i] : 0;
#pragma unroll
    for (int off = 32; off > 0; off >>= 1) s += __shfl_down(s, off, 64);
    if (lane == 0) partials[blockIdx.x] = s;
}

__global__ void k_scan_partials(int* __restrict__ partials, int nb) {
    if (threadIdx.x == 0 && blockIdx.x == 0) {
        int run = 0;
        for (int i = 0; i < nb; ++i) { int v = partials[i]; partials[i] = run; run += v; }
    }
}

__global__ __launch_bounds__(64) void k_scan_chunks(const int* __restrict__ deg,
                                                    const int* __restrict__ partials,
                                                    int* __restrict__ row_start,
                                                    int* __restrict__ cursor, int N) {
    int lane = threadIdx.x;
    int base = blockIdx.x * SCAN_CHUNK + lane * 8;
    int v[8]; int lsum = 0;
#pragma unroll
    for (int i = 0; i < 8; ++i) { v[i] = (base + i < N) ? deg[base + i] : 0; lsum += v[i]; }
    int pre = lsum;
#pragma unroll
    for (int off = 1; off < 64; off <<= 1) {
        int t = __shfl_up(pre, off, 64);
        if (lane >= off) pre += t;
    }
    pre -= lsum;
    int run = partials[blockIdx.x] + pre;
#pragma unroll
    for (int i = 0; i < 8; ++i) {
        if (base + i < N) { row_start[base + i] = run; cursor[base + i] = run; }
        run += v[i];
    }
}

// csr[pos] = {src, eid} packed
__global__ void k_bucket(const int* __restrict__ src, const int* __restrict__ dst,
                         int* __restrict__ cursor, int2* __restrict__ csr, int E) {
    int e = blockIdx.x * blockDim.x + threadIdx.x;
    if (e < E) {
        int pos = atomicAdd(&cursor[dst[e]], 1);
        csr[pos] = make_int2(src[e], e);
    }
}

// ---------------- cast x -> bf16 ----------------
__global__ __launch_bounds__(256) void k_cast(const float* __restrict__ x,
                                              ushort_t* __restrict__ xb, int n4) {
    int i = blockIdx.x * blockDim.x + threadIdx.x;
    if (i >= n4) return;
    float4 v = ((const float4*)x)[i];
    ushort4 o;
    o.x = f2b(v.x); o.y = f2b(v.y); o.z = f2b(v.z); o.w = f2b(v.w);
    ((ushort4*)xb)[i] = o;
}

// ---------------- weight prep: fp32 [256][256] -> MFMA B-frag order, single bf16 plane ------
__global__ __launch_bounds__(64) void k_wprep(const float* __restrict__ Wsrc,
                                              ushort_t* __restrict__ WF,
                                              int nbTot, int nb0) {
    int lane = threadIdx.x;
    int kb = blockIdx.x >> 4, nbL = blockIdx.x & 15;
    int k = kb * 32 + (lane >> 4) * 8;
    int n = nbL * 16 + (lane & 15);
    size_t dstb = (size_t)(kb * nbTot + nb0 + nbL) * 512 + lane * 8;
#pragma unroll
    for (int j = 0; j < 8; ++j) {
        WF[dstb + j] = f2b(Wsrc[(size_t)(k + j) * 256 + n]);
    }
}

// ---------------- gather-aggregate (R7 form): one wave/node, 4 rows in flight --------------
__global__ __launch_bounds__(256) void k_gather(const ushort_t* __restrict__ X,
                                                const int2* __restrict__ csr,
                                                const int* __restrict__ row_start,
                                                const int* __restrict__ deg,
                                                ushort_t* __restrict__ agg, int N) {
    int lane = threadIdx.x & 63;
    int node = blockIdx.x * 4 + (threadIdx.x >> 6);
    if (node >= N) return;
    int quad = lane >> 4, l16 = lane & 15;
    int start = row_start[node];
    int cnt = deg[node];
    const int2* sp = csr + start;
    float acc[16] = {};
    for (int b = 0; b < cnt; b += 64) {
        int nb = min(64, cnt - b);
        int sidx = (lane < nb) ? sp[b + lane].x : 0;   // one coalesced batch load
        for (int j4 = 0; j4 < nb; j4 += 4) {           // uniform across the wave
            int j = j4 + quad;
            bool valid = j < nb;
            int s = __shfl(sidx, valid ? j : 0, 64);   // full exec at the shfl
            if (valid) {
                const ushort_t* row = X + (size_t)s * HID + l16 * 16;
                short8 v0 = *(const short8*)(row);
                short8 v1 = *(const short8*)(row + 8);
#pragma unroll
                for (int i = 0; i < 8; ++i) {
                    acc[i]     += b2f((ushort_t)v0[i]);
                    acc[8 + i] += b2f((ushort_t)v1[i]);
                }
            }
        }
    }
#pragma unroll
    for (int i = 0; i < 16; ++i) {
        acc[i] += __shfl_down(acc[i], 32, 64);
        acc[i] += __shfl_down(acc[i], 16, 64);
    }
    if (quad == 0) {
        float sc = 1.0f / (float)max(cnt, 1);
        short8 o0, o1;
#pragma unroll
        for (int i = 0; i < 8; ++i) {
            o0[i] = (short)f2b(acc[i] * sc);
            o1[i] = (short)f2b(acc[8 + i] * sc);
        }
        ushort_t* op = agg + (size_t)node * HID + l16 * 16;
        *(short8*)(op) = o0;
        *(short8*)(op + 8) = o1;
    }
}

// ---------------- MFMA GEMM: whole-tile LDS staging, 4 barriers/block ----------------------
// A-tile (64x256 bf16, padded rows) staged ONCE per operand; K-loop is pure
// ds_read_b128 + coalesced B-frag global loads + MFMA. Single bf16 weight plane.
__global__ __launch_bounds__(256) void k_mfma(const ushort_t* __restrict__ A1,
                                              const ushort_t* __restrict__ WF1,
                                              const ushort_t* __restrict__ A2,
                                              const ushort_t* __restrict__ WF2,
                                              const float* __restrict__ bias, int relu,
                                              int M, int nbTot,
                                              ushort_t* __restrict__ C,
                                              ushort_t* __restrict__ C2) {
    __shared__ ushort_t As[64 * PADW];   // 33.8 KB
    const int tid = threadIdx.x;
    const int lane = tid & 63;
    const int w = tid >> 6;
    const int wm = w >> 1, wn = w & 1;
    const int quad = lane >> 4, l16 = lane & 15;
    const int m0 = blockIdx.y * 64;
    const int n0 = blockIdx.x * 64;
    const int nbBase = (n0 >> 4) + wn * 2;

    floatx4 acc[2][2] = {};

    for (int op = 0; op < 2; ++op) {
        const ushort_t* A = op ? A2 : A1;
        const ushort_t* WF = op ? WF2 : WF1;
        if (A == nullptr) continue;
        if (op) __syncthreads();             // protect previous op's LDS reads
        // stage whole 64x256 tile: 8 x 16B chunks per thread, coalesced
#pragma unroll
        for (int i = 0; i < 8; ++i) {
            int c = i * 256 + tid;           // 16B-chunk id; 32 chunks per row
            int row = c >> 5, col = c & 31;
            int arow = m0 + row; if (arow >= M) arow = M - 1;
            *(uint4*)&As[row * PADW + col * 8] =
                *(const uint4*)(A + (size_t)arow * 256 + col * 8);
        }
        __syncthreads();

        const ushort_t* a0p = &As[(wm * 32 + l16) * PADW + quad * 8];
        const ushort_t* a1p = a0p + 16 * PADW;
        const ushort_t* wp = WF + (size_t)nbBase * 512 + lane * 8;
#pragma unroll
        for (int kb = 0; kb < 8; ++kb) {
            short8 a0 = *(const short8*)(a0p + kb * 32);
            short8 a1 = *(const short8*)(a1p + kb * 32);
            const ushort_t* wkb = wp + (size_t)kb * nbTot * 512;
            short8 b0 = *(const short8*)(wkb);
            short8 b1 = *(const short8*)(wkb + 512);
            acc[0][0] = __builtin_amdgcn_mfma_f32_16x16x32_bf16(a0, b0, acc[0][0], 0, 0, 0);
            acc[0][1] = __builtin_amdgcn_mfma_f32_16x16x32_bf16(a0, b1, acc[0][1], 0, 0, 0);
            acc[1][0] = __builtin_amdgcn_mfma_f32_16x16x32_bf16(a1, b0, acc[1][0], 0, 0, 0);
            acc[1][1] = __builtin_amdgcn_mfma_f32_16x16x32_bf16(a1, b1, acc[1][1], 0, 0, 0);
        }
    }

    // epilogue: C/D layout col=lane&15, row=(lane>>4)*4+reg
#pragma unroll
    for (int mi = 0; mi < 2; ++mi) {
#pragma unroll
        for (int nj = 0; nj < 2; ++nj) {
            int col = n0 + wn * 32 + nj * 16 + l16;
            float b = bias ? bias[col] : 0.f;
            int rbase = m0 + wm * 32 + mi * 16 + quad * 4;
            ushort_t* dstp = C;
            int c = col;
            if (C2 && col >= 256) { dstp = C2; c = col - 256; }
#pragma unroll
            for (int reg = 0; reg < 4; ++reg) {
                int r = rbase + reg;
                if (r >= M) continue;
                float v = acc[mi][nj][reg] + b;
                if (relu) v = fmaxf(v, 0.f);
                dstp[(size_t)r * 256 + c] = f2b(v);
            }
        }
    }
}

// ---------------- edge MLP: persistent waves, half-wave per edge, unroll 2, batched idx ------
__global__ __launch_bounds__(256) void k_edge(const ushort_t* __restrict__ P,
                                              const ushort_t* __restrict__ Q,
                                              const int2* __restrict__ csr,
                                              const int* __restrict__ row_start,
                                              const int* __restrict__ deg,
                                              const float* __restrict__ bm1,
                                              const float* __restrict__ Wm2,
                                              const float* __restrict__ bm2,
                                              float* __restrict__ out, int N, int stride) {
    int lane = threadIdx.x & 63;
    int wid = blockIdx.x * 4 + (threadIdx.x >> 6);
    int half = lane >> 5, l32 = lane & 31;

    float w0[8], w1[8], bb[8];
    const float* bp = bm1 + l32 * 8;
    const float2* wp = (const float2*)Wm2 + l32 * 8;
#pragma unroll
    for (int i = 0; i < 8; ++i) {
        float2 wv = wp[i];
        w0[i] = wv.x; w1[i] = wv.y;
        bb[i] = bp[i];
    }
    float bo0 = bm2[0], bo1 = bm2[1];

    for (int node = wid; node < N; node += stride) {
        int start = row_start[node];
        int cnt = deg[node];
        if (cnt == 0) continue;

        short8 qv = *(const short8*)(Q + (size_t)node * HID + l32 * 8);
        float qb[8];
#pragma unroll
        for (int i = 0; i < 8; ++i) qb[i] = b2f((ushort_t)qv[i]) + bb[i];

        const int2* sp = csr + start;
        for (int b = 0; b < cnt; b += 64) {
            int nb = min(64, cnt - b);
            int2 se = (lane < nb) ? sp[b + lane] : make_int2(0, 0);
            for (int j0 = 0; j0 < nb; j0 += 4) {
                int jA = j0 + half;
                int jB = j0 + 2 + half;
                bool vA = jA < nb, vB = jB < nb;
                int iA = vA ? jA : 0, iB = vB ? jB : 0;
                int sA = __shfl(se.x, iA, 64);
                int sB = __shfl(se.x, iB, 64);
                short8 pA = *(const short8*)(P + (size_t)sA * HID + l32 * 8);
                short8 pB = *(const short8*)(P + (size_t)sB * HID + l32 * 8);
                float aA0 = 0.f, aA1 = 0.f, aB0 = 0.f, aB1 = 0.f;
#pragma unroll
                for (int i = 0; i < 8; ++i) {
                    float hA = fmaxf(b2f((ushort_t)pA[i]) + qb[i], 0.f);
                    float hB = fmaxf(b2f((ushort_t)pB[i]) + qb[i], 0.f);
                    aA0 += hA * w0[i]; aA1 += hA * w1[i];
                    aB0 += hB * w0[i]; aB1 += hB * w1[i];
                }
#pragma unroll
                for (int off = 16; off > 0; off >>= 1) {
                    aA0 += __shfl_down(aA0, off, 32);
                    aA1 += __shfl_down(aA1, off, 32);
                    aB0 += __shfl_down(aB0, off, 32);
                    aB1 += __shfl_down(aB1, off, 32);
                }
                int eA = __shfl(se.y, iA, 64);
                int eB = __shfl(se.y, iB, 64);
                if (l32 == 0) {
                    if (vA) {
                        float2 o; o.x = aA0 + bo0; o.y = aA1 + bo1;
                        ((float2*)out)[eA] = o;
                    }
                    if (vB) {
                        float2 o; o.x = aB0 + bo0; o.y = aB1 + bo1;
                        ((float2*)out)[eB] = o;
                    }
                }
            }
        }
    }
}

extern "C" void kernel_launch(void* const* d_in, const int* in_sizes, int n_in,
                              void* d_out, int out_size, void* d_ws, size_t ws_size,
                              hipStream_t stream) {
    const float* x   = (const float*)d_in[0];
    const int*   ei  = (const int*)d_in[1];
    const float* W1l = (const float*)d_in[2];
    const float* b1l = (const float*)d_in[3];
    const float* W1r = (const float*)d_in[4];
    const float* W2l = (const float*)d_in[5];
    const float* b2l = (const float*)d_in[6];
    const float* W2r = (const float*)d_in[7];
    const float* Wm1 = (const float*)d_in[8];
    const float* bm1 = (const float*)d_in[9];
    const float* Wm2 = (const float*)d_in[10];
    const float* bm2 = (const float*)d_in[11];

    const int N = in_sizes[0] / IN_DIM;   // 50000
    const int E = in_sizes[1] / 2;        // 800000
    const int* src = ei;
    const int* dst = ei + E;
    const int NB = (N + SCAN_CHUNK - 1) / SCAN_CHUNK;

    // ---- workspace ----
    char* ws = (char*)d_ws;
    size_t off = 0;
    auto alloc = [&](size_t bytes) { void* p = ws + off; off = (off + bytes + 255) & ~(size_t)255; return p; };
    int* deg       = (int*)alloc((size_t)N * 4);
    int* row_start = (int*)alloc((size_t)N * 4);
    int* cursor    = (int*)alloc((size_t)N * 4);
    int* partials  = (int*)alloc((size_t)(NB + 1) * 4);
    int2* csr      = (int2*)alloc((size_t)E * 8);
    size_t matB = (size_t)N * HID * sizeof(ushort_t);          // 25.6 MB
    ushort_t* xb   = (ushort_t*)alloc(matB);
    ushort_t* aggB = (ushort_t*)alloc(matB);
    ushort_t* h1b  = (ushort_t*)alloc(matB);
    ushort_t* h2b  = (ushort_t*)alloc(matB);
    ushort_t* Pb   = (ushort_t*)alloc(matB);
    ushort_t* Qb   = (ushort_t*)alloc(matB);
    size_t wfB  = (size_t)8 * 16 * 512 * sizeof(ushort_t);      // 128 KB (single plane)
    ushort_t* WF1l = (ushort_t*)alloc(wfB);
    ushort_t* WF1r = (ushort_t*)alloc(wfB);
    ushort_t* WF2l = (ushort_t*)alloc(wfB);
    ushort_t* WF2r = (ushort_t*)alloc(wfB);
    ushort_t* WFm  = (ushort_t*)alloc(wfB * 2);                 // nbTot=32
    float* out = (float*)d_out;

    int nwg = (N + 3) / 4;
    int mrows = (N + 63) / 64;

    // ---- CSR build ----
    hipMemsetAsync(deg, 0, (size_t)N * 4, stream);
    k_count_deg<<<(E + 255) / 256, 256, 0, stream>>>(dst, deg, E);
    k_chunk_sum<<<NB, 64, 0, stream>>>(deg, partials, N);
    k_scan_partials<<<1, 64, 0, stream>>>(partials, NB);
    k_scan_chunks<<<NB, 64, 0, stream>>>(deg, partials, row_start, cursor, N);
    k_bucket<<<(E + 255) / 256, 256, 0, stream>>>(src, dst, cursor, csr, E);

    // ---- casts / weight prep ----
    k_cast<<<(N * HID / 4 + 255) / 256, 256, 0, stream>>>(x, xb, N * HID / 4);
    k_wprep<<<128, 64, 0, stream>>>(W1l, WF1l, 16, 0);
    k_wprep<<<128, 64, 0, stream>>>(W1r, WF1r, 16, 0);
    k_wprep<<<128, 64, 0, stream>>>(W2l, WF2l, 16, 0);
    k_wprep<<<128, 64, 0, stream>>>(W2r, WF2r, 16, 0);
    k_wprep<<<128, 64, 0, stream>>>(Wm1, WFm, 32, 0);
    k_wprep<<<128, 64, 0, stream>>>(Wm1 + (size_t)256 * 256, WFm, 32, 16);

    // ---- conv1 ----
    k_gather<<<nwg, 256, 0, stream>>>(xb, csr, row_start, deg, aggB, N);
    k_mfma<<<dim3(4, mrows), 256, 0, stream>>>(aggB, WF1l, xb, WF1r, b1l, 1, N, 16, h1b, nullptr);

    // ---- conv2 ----
    k_gather<<<nwg, 256, 0, stream>>>(h1b, csr, row_start, deg, aggB, N);
    k_mfma<<<dim3(4, mrows), 256, 0, stream>>>(aggB, WF2l, h1b, WF2r, b2l, 1, N, 16, h2b, nullptr);

    // ---- P|Q fused GEMM -> Pb, Qb ----
    k_mfma<<<dim3(8, mrows), 256, 0, stream>>>(h2b, WFm, nullptr, nullptr, nullptr, 0, N, 32, Pb, Qb);

    // ---- edge MLP (persistent waves) ----
    const int EB = 2048;                  // 8 blocks/CU
    k_edge<<<EB, 256, 0, stream>>>(Pb, Qb, csr, row_start, deg, bm1, Wm2, bm2, out, N, EB * 4);
}

// Round 10
// 564.458 us; speedup vs baseline: 1.0872x; 1.0146x over previous
//
#include <hip/hip_runtime.h>

#define IN_DIM 256
#define HID 256
#define SCAN_CHUNK 512
#define PADW 264   // 256 + 16 ushort pad

typedef unsigned short ushort_t;
typedef __attribute__((ext_vector_type(8))) short short8;
typedef __attribute__((ext_vector_type(4))) float floatx4;

__device__ __forceinline__ float b2f(ushort_t h) {
    union { unsigned int u; float f; } c; c.u = ((unsigned int)h) << 16; return c.f;
}
__device__ __forceinline__ ushort_t f2b(float f) {  // round-to-nearest-even
    union { float f; unsigned int u; } c; c.f = f;
    unsigned int u = c.u;
    unsigned int r = (u + 0x7fffu + ((u >> 16) & 1u)) >> 16;
    return (ushort_t)r;
}

// ---------------- degree ----------------
__global__ void k_count_deg(const int* __restrict__ dst, int* __restrict__ deg, int E) {
    int e = blockIdx.x * blockDim.x + threadIdx.x;
    if (e < E) atomicAdd(&deg[dst[e]], 1);
}

// ---------------- scan ----------------
__global__ __launch_bounds__(64) void k_chunk_sum(const int* __restrict__ deg,
                                                  int* __restrict__ partials, int N) {
    int lane = threadIdx.x;
    int base = blockIdx.x * SCAN_CHUNK + lane * 8;
    int s = 0;
#pragma unroll
    for (int i = 0; i < 8; ++i) s += (base + i < N) ? deg[base + i] : 0;
#pragma unroll
    for (int off = 32; off > 0; off >>= 1) s += __shfl_down(s, off, 64);
    if (lane == 0) partials[blockIdx.x] = s;
}

__global__ void k_scan_partials(int* __restrict__ partials, int nb) {
    if (threadIdx.x == 0 && blockIdx.x == 0) {
        int run = 0;
        for (int i = 0; i < nb; ++i) { int v = partials[i]; partials[i] = run; run += v; }
    }
}

__global__ __launch_bounds__(64) void k_scan_chunks(const int* __restrict__ deg,
                                                    const int* __restrict__ partials,
                                                    int* __restrict__ row_start,
                                                    int* __restrict__ cursor, int N) {
    int lane = threadIdx.x;
    int base = blockIdx.x * SCAN_CHUNK + lane * 8;
    int v[8]; int lsum = 0;
#pragma unroll
    for (int i = 0; i < 8; ++i) { v[i] = (base + i < N) ? deg[base + i] : 0; lsum += v[i]; }
    int pre = lsum;
#pragma unroll
    for (int off = 1; off < 64; off <<= 1) {
        int t = __shfl_up(pre, off, 64);
        if (lane >= off) pre += t;
    }
    pre -= lsum;
    int run = partials[blockIdx.x] + pre;
#pragma unroll
    for (int i = 0; i < 8; ++i) {
        if (base + i < N) { row_start[base + i] = run; cursor[base + i] = run; }
        run += v[i];
    }
}

// csr[pos] = {src, eid} packed
__global__ void k_bucket(const int* __restrict__ src, const int* __restrict__ dst,
                         int* __restrict__ cursor, int2* __restrict__ csr, int E) {
    int e = blockIdx.x * blockDim.x + threadIdx.x;
    if (e < E) {
        int pos = atomicAdd(&cursor[dst[e]], 1);
        csr[pos] = make_int2(src[e], e);
    }
}

// ---------------- cast x -> bf16 ----------------
__global__ __launch_bounds__(256) void k_cast(const float* __restrict__ x,
                                              ushort_t* __restrict__ xb, int n4) {
    int i = blockIdx.x * blockDim.x + threadIdx.x;
    if (i >= n4) return;
    float4 v = ((const float4*)x)[i];
    ushort4 o;
    o.x = f2b(v.x); o.y = f2b(v.y); o.z = f2b(v.z); o.w = f2b(v.w);
    ((ushort4*)xb)[i] = o;
}

// ---------------- weight prep: fp32 [256][256] -> MFMA B-frag order, single bf16 plane ------
__global__ __launch_bounds__(64) void k_wprep(const float* __restrict__ Wsrc,
                                              ushort_t* __restrict__ WF,
                                              int nbTot, int nb0) {
    int lane = threadIdx.x;
    int kb = blockIdx.x >> 4, nbL = blockIdx.x & 15;
    int k = kb * 32 + (lane >> 4) * 8;
    int n = nbL * 16 + (lane & 15);
    size_t dstb = (size_t)(kb * nbTot + nb0 + nbL) * 512 + lane * 8;
#pragma unroll
    for (int j = 0; j < 8; ++j) {
        WF[dstb + j] = f2b(Wsrc[(size_t)(k + j) * 256 + n]);
    }
}

// ---------------- gather-aggregate: one wave/node, 8 rows in flight, batched indices --------
// Wave-uniform inner loop; shfl under full exec; loads unconditional (clamped idx), adds predicated.
__global__ __launch_bounds__(256) void k_gather(const ushort_t* __restrict__ X,
                                                const int2* __restrict__ csr,
                                                const int* __restrict__ row_start,
                                                const int* __restrict__ deg,
                                                ushort_t* __restrict__ agg, int N) {
    int lane = threadIdx.x & 63;
    int node = blockIdx.x * 4 + (threadIdx.x >> 6);
    if (node >= N) return;
    int quad = lane >> 4, l16 = lane & 15;
    int start = row_start[node];
    int cnt = deg[node];
    const int2* sp = csr + start;
    float acc[16] = {};
    for (int b = 0; b < cnt; b += 64) {
        int nb = min(64, cnt - b);
        int sidx = (lane < nb) ? sp[b + lane].x : 0;   // one coalesced batch load
        for (int j8 = 0; j8 < nb; j8 += 8) {           // uniform across the wave
            int jA = j8 + quad, jB = j8 + 4 + quad;
            bool vA = jA < nb, vB = jB < nb;
            int sA = __shfl(sidx, vA ? jA : 0, 64);
            int sB = __shfl(sidx, vB ? jB : 0, 64);
            const ushort_t* rowA = X + (size_t)sA * HID + l16 * 16;
            const ushort_t* rowB = X + (size_t)sB * HID + l16 * 16;
            short8 a0 = *(const short8*)(rowA);
            short8 a1 = *(const short8*)(rowA + 8);
            short8 b0 = *(const short8*)(rowB);
            short8 b1 = *(const short8*)(rowB + 8);
            if (vA) {
#pragma unroll
                for (int i = 0; i < 8; ++i) {
                    acc[i]     += b2f((ushort_t)a0[i]);
                    acc[8 + i] += b2f((ushort_t)a1[i]);
                }
            }
            if (vB) {
#pragma unroll
                for (int i = 0; i < 8; ++i) {
                    acc[i]     += b2f((ushort_t)b0[i]);
                    acc[8 + i] += b2f((ushort_t)b1[i]);
                }
            }
        }
    }
#pragma unroll
    for (int i = 0; i < 16; ++i) {
        acc[i] += __shfl_down(acc[i], 32, 64);
        acc[i] += __shfl_down(acc[i], 16, 64);
    }
    if (quad == 0) {
        float sc = 1.0f / (float)max(cnt, 1);
        short8 o0, o1;
#pragma unroll
        for (int i = 0; i < 8; ++i) {
            o0[i] = (short)f2b(acc[i] * sc);
            o1[i] = (short)f2b(acc[8 + i] * sc);
        }
        ushort_t* op = agg + (size_t)node * HID + l16 * 16;
        *(short8*)(op) = o0;
        *(short8*)(op + 8) = o1;
    }
}

// ---------------- MFMA GEMM: whole-tile LDS staging, 4 barriers/block (R9) -----------------
__global__ __launch_bounds__(256) void k_mfma(const ushort_t* __restrict__ A1,
                                              const ushort_t* __restrict__ WF1,
                                              const ushort_t* __restrict__ A2,
                                              const ushort_t* __restrict__ WF2,
                                              const float* __restrict__ bias, int relu,
                                              int M, int nbTot,
                                              ushort_t* __restrict__ C,
                                              ushort_t* __restrict__ C2) {
    __shared__ ushort_t As[64 * PADW];   // 33.8 KB
    const int tid = threadIdx.x;
    const int lane = tid & 63;
    const int w = tid >> 6;
    const int wm = w >> 1, wn = w & 1;
    const int quad = lane >> 4, l16 = lane & 15;
    const int m0 = blockIdx.y * 64;
    const int n0 = blockIdx.x * 64;
    const int nbBase = (n0 >> 4) + wn * 2;

    floatx4 acc[2][2] = {};

    for (int op = 0; op < 2; ++op) {
        const ushort_t* A = op ? A2 : A1;
        const ushort_t* WF = op ? WF2 : WF1;
        if (A == nullptr) continue;
        if (op) __syncthreads();
#pragma unroll
        for (int i = 0; i < 8; ++i) {
            int c = i * 256 + tid;
            int row = c >> 5, col = c & 31;
            int arow = m0 + row; if (arow >= M) arow = M - 1;
            *(uint4*)&As[row * PADW + col * 8] =
                *(const uint4*)(A + (size_t)arow * 256 + col * 8);
        }
        __syncthreads();

        const ushort_t* a0p = &As[(wm * 32 + l16) * PADW + quad * 8];
        const ushort_t* a1p = a0p + 16 * PADW;
        const ushort_t* wp = WF + (size_t)nbBase * 512 + lane * 8;
#pragma unroll
        for (int kb = 0; kb < 8; ++kb) {
            short8 a0 = *(const short8*)(a0p + kb * 32);
            short8 a1 = *(const short8*)(a1p + kb * 32);
            const ushort_t* wkb = wp + (size_t)kb * nbTot * 512;
            short8 b0 = *(const short8*)(wkb);
            short8 b1 = *(const short8*)(wkb + 512);
            acc[0][0] = __builtin_amdgcn_mfma_f32_16x16x32_bf16(a0, b0, acc[0][0], 0, 0, 0);
            acc[0][1] = __builtin_amdgcn_mfma_f32_16x16x32_bf16(a0, b1, acc[0][1], 0, 0, 0);
            acc[1][0] = __builtin_amdgcn_mfma_f32_16x16x32_bf16(a1, b0, acc[1][0], 0, 0, 0);
            acc[1][1] = __builtin_amdgcn_mfma_f32_16x16x32_bf16(a1, b1, acc[1][1], 0, 0, 0);
        }
    }

#pragma unroll
    for (int mi = 0; mi < 2; ++mi) {
#pragma unroll
        for (int nj = 0; nj < 2; ++nj) {
            int col = n0 + wn * 32 + nj * 16 + l16;
            float b = bias ? bias[col] : 0.f;
            int rbase = m0 + wm * 32 + mi * 16 + quad * 4;
            ushort_t* dstp = C;
            int c = col;
            if (C2 && col >= 256) { dstp = C2; c = col - 256; }
#pragma unroll
            for (int reg = 0; reg < 4; ++reg) {
                int r = rbase + reg;
                if (r >= M) continue;
                float v = acc[mi][nj][reg] + b;
                if (relu) v = fmaxf(v, 0.f);
                dstp[(size_t)r * 256 + c] = f2b(v);
            }
        }
    }
}

// ---------------- edge MLP: persistent waves, 8 edges/iter (4 per half-wave) ----------------
// All __shfl execute under full exec: loop is wave-uniform, validity via ternaries.
__global__ __launch_bounds__(256) void k_edge(const ushort_t* __restrict__ P,
                                              const ushort_t* __restrict__ Q,
                                              const int2* __restrict__ csr,
                                              const int* __restrict__ row_start,
                                              const int* __restrict__ deg,
                                              const float* __restrict__ bm1,
                                              const float* __restrict__ Wm2,
                                              const float* __restrict__ bm2,
                                              float* __restrict__ out, int N, int stride) {
    int lane = threadIdx.x & 63;
    int wid = blockIdx.x * 4 + (threadIdx.x >> 6);
    int half = lane >> 5, l32 = lane & 31;

    float w0[8], w1[8], bb[8];
    const float* bp = bm1 + l32 * 8;
    const float2* wp = (const float2*)Wm2 + l32 * 8;
#pragma unroll
    for (int i = 0; i < 8; ++i) {
        float2 wv = wp[i];
        w0[i] = wv.x; w1[i] = wv.y;
        bb[i] = bp[i];
    }
    float bo0 = bm2[0], bo1 = bm2[1];

    for (int node = wid; node < N; node += stride) {
        int start = row_start[node];
        int cnt = deg[node];
        if (cnt == 0) continue;

        short8 qv = *(const short8*)(Q + (size_t)node * HID + l32 * 8);
        float qb[8];
#pragma unroll
        for (int i = 0; i < 8; ++i) qb[i] = b2f((ushort_t)qv[i]) + bb[i];

        const int2* sp = csr + start;
        for (int b = 0; b < cnt; b += 64) {
            int nb = min(64, cnt - b);
            int2 se = (lane < nb) ? sp[b + lane] : make_int2(0, 0);
            for (int j0 = 0; j0 < nb; j0 += 8) {
                int jA = j0 + half, jB = j0 + 2 + half, jC = j0 + 4 + half, jD = j0 + 6 + half;
                bool vA = jA < nb, vB = jB < nb, vC = jC < nb, vD = jD < nb;
                int iA = vA ? jA : 0, iB = vB ? jB : 0, iC = vC ? jC : 0, iD = vD ? jD : 0;
                int sA = __shfl(se.x, iA, 64);
                int sB = __shfl(se.x, iB, 64);
                int sC = __shfl(se.x, iC, 64);
                int sD = __shfl(se.x, iD, 64);
                short8 pA = *(const short8*)(P + (size_t)sA * HID + l32 * 8);
                short8 pB = *(const short8*)(P + (size_t)sB * HID + l32 * 8);
                short8 pC = *(const short8*)(P + (size_t)sC * HID + l32 * 8);
                short8 pD = *(const short8*)(P + (size_t)sD * HID + l32 * 8);
                float aA0 = 0.f, aA1 = 0.f, aB0 = 0.f, aB1 = 0.f;
                float aC0 = 0.f, aC1 = 0.f, aD0 = 0.f, aD1 = 0.f;
#pragma unroll
                for (int i = 0; i < 8; ++i) {
                    float hA = fmaxf(b2f((ushort_t)pA[i]) + qb[i], 0.f);
                    float hB = fmaxf(b2f((ushort_t)pB[i]) + qb[i], 0.f);
                    float hC = fmaxf(b2f((ushort_t)pC[i]) + qb[i], 0.f);
                    float hD = fmaxf(b2f((ushort_t)pD[i]) + qb[i], 0.f);
                    aA0 += hA * w0[i]; aA1 += hA * w1[i];
                    aB0 += hB * w0[i]; aB1 += hB * w1[i];
                    aC0 += hC * w0[i]; aC1 += hC * w1[i];
                    aD0 += hD * w0[i]; aD1 += hD * w1[i];
                }
#pragma unroll
                for (int off = 16; off > 0; off >>= 1) {
                    aA0 += __shfl_down(aA0, off, 32);
                    aA1 += __shfl_down(aA1, off, 32);
                    aB0 += __shfl_down(aB0, off, 32);
                    aB1 += __shfl_down(aB1, off, 32);
                    aC0 += __shfl_down(aC0, off, 32);
                    aC1 += __shfl_down(aC1, off, 32);
                    aD0 += __shfl_down(aD0, off, 32);
                    aD1 += __shfl_down(aD1, off, 32);
                }
                int eA = __shfl(se.y, iA, 64);
                int eB = __shfl(se.y, iB, 64);
                int eC = __shfl(se.y, iC, 64);
                int eD = __shfl(se.y, iD, 64);
                if (l32 == 0) {
                    if (vA) { float2 o; o.x = aA0 + bo0; o.y = aA1 + bo1; ((float2*)out)[eA] = o; }
                    if (vB) { float2 o; o.x = aB0 + bo0; o.y = aB1 + bo1; ((float2*)out)[eB] = o; }
                    if (vC) { float2 o; o.x = aC0 + bo0; o.y = aC1 + bo1; ((float2*)out)[eC] = o; }
                    if (vD) { float2 o; o.x = aD0 + bo0; o.y = aD1 + bo1; ((float2*)out)[eD] = o; }
                }
            }
        }
    }
}

extern "C" void kernel_launch(void* const* d_in, const int* in_sizes, int n_in,
                              void* d_out, int out_size, void* d_ws, size_t ws_size,
                              hipStream_t stream) {
    const float* x   = (const float*)d_in[0];
    const int*   ei  = (const int*)d_in[1];
    const float* W1l = (const float*)d_in[2];
    const float* b1l = (const float*)d_in[3];
    const float* W1r = (const float*)d_in[4];
    const float* W2l = (const float*)d_in[5];
    const float* b2l = (const float*)d_in[6];
    const float* W2r = (const float*)d_in[7];
    const float* Wm1 = (const float*)d_in[8];
    const float* bm1 = (const float*)d_in[9];
    const float* Wm2 = (const float*)d_in[10];
    const float* bm2 = (const float*)d_in[11];

    const int N = in_sizes[0] / IN_DIM;   // 50000
    const int E = in_sizes[1] / 2;        // 800000
    const int* src = ei;
    const int* dst = ei + E;
    const int NB = (N + SCAN_CHUNK - 1) / SCAN_CHUNK;

    // ---- workspace ----
    char* ws = (char*)d_ws;
    size_t off = 0;
    auto alloc = [&](size_t bytes) { void* p = ws + off; off = (off + bytes + 255) & ~(size_t)255; return p; };
    int* deg       = (int*)alloc((size_t)N * 4);
    int* row_start = (int*)alloc((size_t)N * 4);
    int* cursor    = (int*)alloc((size_t)N * 4);
    int* partials  = (int*)alloc((size_t)(NB + 1) * 4);
    int2* csr      = (int2*)alloc((size_t)E * 8);
    size_t matB = (size_t)N * HID * sizeof(ushort_t);          // 25.6 MB
    ushort_t* xb   = (ushort_t*)alloc(matB);
    ushort_t* aggB = (ushort_t*)alloc(matB);
    ushort_t* h1b  = (ushort_t*)alloc(matB);
    ushort_t* h2b  = (ushort_t*)alloc(matB);
    ushort_t* Pb   = (ushort_t*)alloc(matB);
    ushort_t* Qb   = (ushort_t*)alloc(matB);
    size_t wfB  = (size_t)8 * 16 * 512 * sizeof(ushort_t);      // 128 KB (single plane)
    ushort_t* WF1l = (ushort_t*)alloc(wfB);
    ushort_t* WF1r = (ushort_t*)alloc(wfB);
    ushort_t* WF2l = (ushort_t*)alloc(wfB);
    ushort_t* WF2r = (ushort_t*)alloc(wfB);
    ushort_t* WFm  = (ushort_t*)alloc(wfB * 2);                 // nbTot=32
    float* out = (float*)d_out;

    int nwg = (N + 3) / 4;
    int mrows = (N + 63) / 64;

    // ---- CSR build ----
    hipMemsetAsync(deg, 0, (size_t)N * 4, stream);
    k_count_deg<<<(E + 255) / 256, 256, 0, stream>>>(dst, deg, E);
    k_chunk_sum<<<NB, 64, 0, stream>>>(deg, partials, N);
    k_scan_partials<<<1, 64, 0, stream>>>(partials, NB);
    k_scan_chunks<<<NB, 64, 0, stream>>>(deg, partials, row_start, cursor, N);
    k_bucket<<<(E + 255) / 256, 256, 0, stream>>>(src, dst, cursor, csr, E);

    // ---- casts / weight prep ----
    k_cast<<<(N * HID / 4 + 255) / 256, 256, 0, stream>>>(x, xb, N * HID / 4);
    k_wprep<<<128, 64, 0, stream>>>(W1l, WF1l, 16, 0);
    k_wprep<<<128, 64, 0, stream>>>(W1r, WF1r, 16, 0);
    k_wprep<<<128, 64, 0, stream>>>(W2l, WF2l, 16, 0);
    k_wprep<<<128, 64, 0, stream>>>(W2r, WF2r, 16, 0);
    k_wprep<<<128, 64, 0, stream>>>(Wm1, WFm, 32, 0);
    k_wprep<<<128, 64, 0, stream>>>(Wm1 + (size_t)256 * 256, WFm, 32, 16);

    // ---- conv1 ----
    k_gather<<<nwg, 256, 0, stream>>>(xb, csr, row_start, deg, aggB, N);
    k_mfma<<<dim3(4, mrows), 256, 0, stream>>>(aggB, WF1l, xb, WF1r, b1l, 1, N, 16, h1b, nullptr);

    // ---- conv2 ----
    k_gather<<<nwg, 256, 0, stream>>>(h1b, csr, row_start, deg, aggB, N);
    k_mfma<<<dim3(4, mrows), 256, 0, stream>>>(aggB, WF2l, h1b, WF2r, b2l, 1, N, 16, h2b, nullptr);

    // ---- P|Q fused GEMM -> Pb, Qb ----
    k_mfma<<<dim3(8, mrows), 256, 0, stream>>>(h2b, WFm, nullptr, nullptr, nullptr, 0, N, 32, Pb, Qb);

    // ---- edge MLP (persistent waves) ----
    const int EB = 2048;                  // 8 blocks/CU
    k_edge<<<EB, 256, 0, stream>>>(Pb, Qb, csr, row_start, deg, bm1, Wm2, bm2, out, N, EB * 4);
}